// Round 11
// baseline (4373.949 us; speedup 1.0000x reference)
//
#include <hip/hip_runtime.h>
#include <hip/hip_bf16.h>

// ---------------------------------------------------------------------------
// PointerLSTM: B=64, L=1024, D=256, H=256, T=1024 steps.
//   tanh(x) = 1 - 2/(1 + e^{2x});  e^{2(a+d)} = A*D with A=e^{2a}, D=e^{2d}
//   score_l = const - 2*sum_h V_h/(1+A_lh*D_th)   -> const cancels in softmax
// R10 -> R11:
//  * k3_fat STILL spilled (VGPR_Count=128, ~37MB scratch in WRITE_SIZE):
//    launch_bounds' 2nd arg sets only the waves/EU MINIMUM; allocator kept
//    targeting 4 waves/SIMD -> 128-reg budget. Fix: amdgpu_waves_per_eu(2,2)
//    pins the MAX -> budget 512/2 = 256 regs, weights stay in VGPRs.
//  * k4: ATq re-fetched ~3x across XCD L2s (FETCH 165MB vs 96MB real).
//    Bijective XCD swizzle co-locates same-b blocks per XCD (4096%8==0).
// ---------------------------------------------------------------------------

#define LOG2E  1.4426950408889634f
#define C2LOG2E 2.8853900817779268f   // 2*log2(e)

typedef float f32x2 __attribute__((ext_vector_type(2)));

__device__ __forceinline__ unsigned f2bf(float f) {
  unsigned u = __builtin_bit_cast(unsigned, f);
  return (u + 0x7fffu + ((u >> 16) & 1u)) >> 16;   // round-to-nearest-even
}
// bf16 bits in the LOW half of `bits` -> float. (High half ignored.)
__device__ __forceinline__ float bfbits2f(unsigned bits) {
  return __builtin_bit_cast(float, bits << 16);
}
// bf16 bits in the HIGH half of `bits` -> float (no shift needed).
__device__ __forceinline__ float bfhi2f(unsigned bits) {
  return __builtin_bit_cast(float, bits & 0xffff0000u);
}

// lgkmcnt-only barrier: skips __syncthreads()'s vmcnt(0) drain (in-flight
// global stores are NOT needed by the other threads; only LDS data crosses).
#define CHEAP_BAR()                                            \
  do {                                                         \
    asm volatile("s_waitcnt lgkmcnt(0)\n\ts_barrier" ::: "memory"); \
    __builtin_amdgcn_sched_barrier(0);                         \
  } while (0)

#if defined(__has_builtin)
#  if __has_builtin(__builtin_amdgcn_fdot2_f32_bf16)
#    define HAS_DOT2_BF16 1
#  endif
#endif

#if defined(HAS_DOT2_BF16)
typedef __bf16 bf16x2v __attribute__((ext_vector_type(2)));
__device__ __forceinline__ float dot2bf(unsigned w, unsigned h, float acc) {
  return __builtin_amdgcn_fdot2_f32_bf16(__builtin_bit_cast(bf16x2v, w),
                                         __builtin_bit_cast(bf16x2v, h), acc, false);
}
#else
__device__ __forceinline__ float dot2bf(unsigned w, unsigned h, float acc) {
  float wl = __builtin_bit_cast(float, w << 16);
  float wh = __builtin_bit_cast(float, w & 0xffff0000u);
  float hl = __builtin_bit_cast(float, h << 16);
  float hh = __builtin_bit_cast(float, h & 0xffff0000u);
  return fmaf(wh, hh, fmaf(wl, hl, acc));
}
#endif

#if defined(__has_builtin) && __has_builtin(__builtin_amdgcn_rcpf)
#  define FAST_RCP(x) __builtin_amdgcn_rcpf(x)
#else
#  define FAST_RCP(x) (1.0f / (x))
#endif

__device__ __forceinline__ float fast_sigmoid(float x) {
  return FAST_RCP(1.f + exp2f(-LOG2E * x));
}
__device__ __forceinline__ float fast_tanh(float x) {
  return 1.f - 2.f * FAST_RCP(1.f + exp2f(C2LOG2E * x));
}

// --- k2: xz[b][j] = x[b][1023][:] @ Wk[:,j] + b[j]
__global__ __launch_bounds__(256) void k2_xz(const float* __restrict__ x,
                                             const float* __restrict__ Wk,
                                             const float* __restrict__ bvec,
                                             float* __restrict__ xz) {
  const int b = blockIdx.x, tid = threadIdx.x;
  float acc[4] = {bvec[tid], bvec[256 + tid], bvec[512 + tid], bvec[768 + tid]};
  const float* xr = x + ((size_t)b * 1024 + 1023) * 256;
  for (int d0 = 0; d0 < 256; d0 += 4) {
    const float4 xv = *(const float4*)(xr + d0);
#pragma unroll
    for (int i = 0; i < 4; ++i) {
      const float xs = (i == 0) ? xv.x : (i == 1) ? xv.y : (i == 2) ? xv.z : xv.w;
#pragma unroll
      for (int q = 0; q < 4; ++q)
        acc[q] = fmaf(xs, Wk[(size_t)(d0 + i) * 1024 + q * 256 + tid], acc[q]);
    }
  }
#pragma unroll
  for (int q = 0; q < 4; ++q) xz[b * 1024 + q * 256 + tid] = acc[q];
}

// --- k3_fat: blocks 0..63 = LSTM recurrence (one per batch);
//             blocks 64..4159 = w1e GEMM (former k1), filling idle CUs.
// amdgpu_waves_per_eu(2,2): pins allocator budget to 512/2=256 VGPRs so the
// 192 weight regs do NOT spill (launch_bounds' 2nd arg only set the MIN).
__global__
__attribute__((amdgpu_flat_work_group_size(512, 512), amdgpu_waves_per_eu(2, 2)))
void k3_fat(const float* __restrict__ xz,
            const float* __restrict__ Wr,
            unsigned short* __restrict__ hseq,
            const float* __restrict__ x,
            const float* __restrict__ W1,
            const float* __restrict__ b1,
            uint2* __restrict__ ATq) {
  __shared__ __align__(16) unsigned smem[8 * 1024 * 4 + 512 + 128];  // 133.6 KiB
  const int tid = threadIdx.x;
  if (blockIdx.x < 64) {
    // ---------------- recurrence path ----------------
    unsigned* Wtail = smem;                       // [8][1024][4]
    float*    z_lds = (float*)(smem + 32768);     // [512]
    unsigned* h_pk  = smem + 32768 + 512;         // [128]
    const int b = blockIdx.x;
    const int colA = tid, colB = tid + 512;

    unsigned wA[96], wB[96];
#pragma unroll
    for (int p = 0; p < 96; ++p) {
      wA[p] = f2bf(Wr[(size_t)(2 * p) * 1024 + colA]) |
              (f2bf(Wr[(size_t)(2 * p + 1) * 1024 + colA]) << 16);
      wB[p] = f2bf(Wr[(size_t)(2 * p) * 1024 + colB]) |
              (f2bf(Wr[(size_t)(2 * p + 1) * 1024 + colB]) << 16);
    }
#pragma unroll
    for (int gg = 0; gg < 8; ++gg) {
#pragma unroll
      for (int d = 0; d < 4; ++d) {
        const int p = 96 + gg * 4 + d;
        Wtail[(gg * 1024 + colA) * 4 + d] =
            f2bf(Wr[(size_t)(2 * p) * 1024 + colA]) |
            (f2bf(Wr[(size_t)(2 * p + 1) * 1024 + colA]) << 16);
        Wtail[(gg * 1024 + colB) * 4 + d] =
            f2bf(Wr[(size_t)(2 * p) * 1024 + colB]) |
            (f2bf(Wr[(size_t)(2 * p + 1) * 1024 + colB]) << 16);
      }
    }
    if (tid < 128) h_pk[tid] = 0u;
    const float zaA = xz[b * 1024 + colA];
    const float zaB = xz[b * 1024 + colB];
    float c = 0.f;
    CHEAP_BAR();

    for (int t = 0; t < 1024; ++t) {
      float aA0 = zaA, aA1 = 0.f, aB0 = zaB, aB1 = 0.f;
#pragma unroll
      for (int g = 0; g < 12; ++g) {
        const uint4 hp = *(const uint4*)&h_pk[4 * g];
        aA0 = dot2bf(wA[4 * g + 0], hp.x, aA0);
        aA0 = dot2bf(wA[4 * g + 1], hp.y, aA0);
        aA0 = dot2bf(wA[4 * g + 2], hp.z, aA0);
        aA0 = dot2bf(wA[4 * g + 3], hp.w, aA0);
        aB0 = dot2bf(wB[4 * g + 0], hp.x, aB0);
        aB0 = dot2bf(wB[4 * g + 1], hp.y, aB0);
        aB0 = dot2bf(wB[4 * g + 2], hp.z, aB0);
        aB0 = dot2bf(wB[4 * g + 3], hp.w, aB0);
      }
#pragma unroll
      for (int g = 12; g < 24; ++g) {
        const uint4 hp = *(const uint4*)&h_pk[4 * g];
        aA1 = dot2bf(wA[4 * g + 0], hp.x, aA1);
        aA1 = dot2bf(wA[4 * g + 1], hp.y, aA1);
        aA1 = dot2bf(wA[4 * g + 2], hp.z, aA1);
        aA1 = dot2bf(wA[4 * g + 3], hp.w, aA1);
        aB1 = dot2bf(wB[4 * g + 0], hp.x, aB1);
        aB1 = dot2bf(wB[4 * g + 1], hp.y, aB1);
        aB1 = dot2bf(wB[4 * g + 2], hp.z, aB1);
        aB1 = dot2bf(wB[4 * g + 3], hp.w, aB1);
      }
#pragma unroll
      for (int gg = 0; gg < 8; ++gg) {
        const uint4 hp = *(const uint4*)&h_pk[96 + 4 * gg];
        const uint4 wa = *(const uint4*)&Wtail[(gg * 1024 + colA) * 4];
        const uint4 wb = *(const uint4*)&Wtail[(gg * 1024 + colB) * 4];
        float& rA = (gg < 4) ? aA0 : aA1;
        float& rB = (gg < 4) ? aB0 : aB1;
        rA = dot2bf(wa.x, hp.x, rA);
        rA = dot2bf(wa.y, hp.y, rA);
        rA = dot2bf(wa.z, hp.z, rA);
        rA = dot2bf(wa.w, hp.w, rA);
        rB = dot2bf(wb.x, hp.x, rB);
        rB = dot2bf(wb.y, hp.y, rB);
        rB = dot2bf(wb.z, hp.z, rB);
        rB = dot2bf(wb.w, hp.w, rB);
      }
      const float aA = aA0 + aA1;
      const float aB = aB0 + aB1;
      // z export: thread>=256 holds zf (colA in [256,512)) and zo (colB in [768,1024))
      if (tid >= 256) {
        z_lds[tid - 256] = aA;      // zf for h-elem (tid-256)
        z_lds[tid]       = aB;      // zo for h-elem (tid-256), offset +256
      }
      CHEAP_BAR();
      // gates: thread<256 owns h-elem tid; zi = own colA, zg = own colB.
      if (tid < 256) {
        const float zi = aA;
        const float zg = aB;
        const float zf = z_lds[tid];
        const float zo = z_lds[tid + 256];
        const float ig = fast_sigmoid(zi);
        const float fg = fast_sigmoid(zf);
        const float gv = fast_tanh(zg);
        const float og = fast_sigmoid(zo);
        c = fmaf(fg, c, ig * gv);
        const float h = og * fast_tanh(c);
        const unsigned short hb = (unsigned short)f2bf(h);
        ((unsigned short*)h_pk)[tid] = hb;
        hseq[(size_t)(t * 64 + b) * 256 + tid] = hb;   // fire-and-forget
      }
      CHEAP_BAR();
    }
  } else {
    // ---------------- w1e GEMM path (former k1) ----------------
    unsigned short* tile = (unsigned short*)smem;     // [256][16], 8 KiB
    const int bid = blockIdx.x - 64;
    const int b  = bid >> 6;
    const int lb = bid & 63;            // 16 l-rows per block
    const int h    = tid & 255;
    const int half = tid >> 8;          // 0: rows 0..7, 1: rows 8..15
    float acc[8];
    const float bias = b1[h];
#pragma unroll
    for (int r = 0; r < 8; ++r) acc[r] = bias;
    const float* xb = x + ((size_t)(b * 1024 + lb * 16 + half * 8)) * 256;
    for (int d0 = 0; d0 < 256; d0 += 4) {
      const float w0 = W1[(d0 + 0) * 256 + h];
      const float w1 = W1[(d0 + 1) * 256 + h];
      const float w2 = W1[(d0 + 2) * 256 + h];
      const float w3 = W1[(d0 + 3) * 256 + h];
#pragma unroll
      for (int r = 0; r < 8; ++r) {
        const float4 xv = *(const float4*)(xb + r * 256 + d0);
        acc[r] = fmaf(xv.x, w0, acc[r]);
        acc[r] = fmaf(xv.y, w1, acc[r]);
        acc[r] = fmaf(xv.z, w2, acc[r]);
        acc[r] = fmaf(xv.w, w3, acc[r]);
      }
    }
#pragma unroll
    for (int r = 0; r < 8; ++r)
      tile[h * 16 + half * 8 + r] = (unsigned short)f2bf(exp2f(C2LOG2E * acc[r]));
    __syncthreads();
    // write phase: 1024 uint2 outputs (hq, lloc), 2 per thread, coalesced.
#pragma unroll
    for (int k = 0; k < 2; ++k) {
      const int o = k * 512 + tid;
      const int hq = o >> 4, lloc = o & 15;
      const unsigned s0 = tile[(4 * hq + 0) * 16 + lloc];
      const unsigned s1 = tile[(4 * hq + 1) * 16 + lloc];
      const unsigned s2 = tile[(4 * hq + 2) * 16 + lloc];
      const unsigned s3 = tile[(4 * hq + 3) * 16 + lloc];
      uint2 val;
      val.x = s0 | (s1 << 16);
      val.y = s2 | (s3 << 16);
      ATq[(((size_t)(b * 64 + hq)) << 10) + lb * 16 + lloc] = val;
    }
  }
}

// --- k3b: w2d = hseq @ W2 + b2 for all (t,b); store D[b][t][h] = f32(exp2(C2*w2d))
__global__ __launch_bounds__(256) void k3b_w2d(const unsigned int* __restrict__ hseq,
                                               const float* __restrict__ W2,
                                               const float* __restrict__ b2,
                                               float* __restrict__ D) {
  const int r0 = blockIdx.x * 16;   // rows (t*64+b); 16 rows share one t
  const int h = threadIdx.x;
  float acc[16];
  const float bias = b2[h];
#pragma unroll
  for (int r = 0; r < 16; ++r) acc[r] = bias;
  for (int m0 = 0; m0 < 128; m0 += 2) {   // 2 dwords = 4 k values
    const float w0 = W2[(size_t)(2 * m0 + 0) * 256 + h];
    const float w1 = W2[(size_t)(2 * m0 + 1) * 256 + h];
    const float w2 = W2[(size_t)(2 * m0 + 2) * 256 + h];
    const float w3 = W2[(size_t)(2 * m0 + 3) * 256 + h];
#pragma unroll
    for (int r = 0; r < 16; ++r) {
      const uint2 hp = *(const uint2*)&hseq[(size_t)(r0 + r) * 128 + m0];
      acc[r] = fmaf(bfbits2f(hp.x),       w0, acc[r]);
      acc[r] = fmaf(bfbits2f(hp.x >> 16), w1, acc[r]);
      acc[r] = fmaf(bfbits2f(hp.y),       w2, acc[r]);
      acc[r] = fmaf(bfbits2f(hp.y >> 16), w3, acc[r]);
    }
  }
  const int t = r0 >> 6;
  const int bb0 = r0 & 63;
#pragma unroll
  for (int r = 0; r < 16; ++r) {
    D[((size_t)(bb0 + r) * 1024 + t) * 256 + h] = exp2f(C2LOG2E * acc[r]);
  }
}

// --- k4: attention scores + softmax (R7 scalar math — known good) + XCD
// swizzle: logical block l = (bid%8)*512 + bid/8 so all 64 t-blocks of one b
// land on one XCD's L2 (ATq slice 512KB re-used instead of re-fetched).
__global__ __launch_bounds__(256, 3) void k4_attn(const uint2* __restrict__ ATq,
                                                  const float* __restrict__ Dm,
                                                  const float* __restrict__ V,
                                                  float* __restrict__ out) {
  const int l  = (blockIdx.x & 7) * 512 + (blockIdx.x >> 3);   // bijective, 4096%8==0
  const int b  = l >> 6;
  const int tb = l & 63;
  const int wv = threadIdx.x >> 6;
  const int lane = threadIdx.x & 63;
  const int t0 = tb * 16 + wv * 4;
  const uint2* Ab = ATq + (((size_t)b) << 16);           // b*64*1024
  const float* Db = Dm + ((size_t)(b * 1024) + t0) * 256;
  f32x2 acc2[2][16];   // [t-pair][lb]; .x = t0+2p, .y = t0+2p+1
#pragma unroll
  for (int p = 0; p < 2; ++p)
#pragma unroll
    for (int lb = 0; lb < 16; ++lb) acc2[p][lb] = (f32x2){0.f, 0.f};

  for (int hq = 0; hq < 64; ++hq) {
    const float4 vq  = *(const float4*)(V + hq * 4);
    const float4 Dr0 = *(const float4*)(Db + 0 * 256 + hq * 4);
    const float4 Dr1 = *(const float4*)(Db + 1 * 256 + hq * 4);
    const float4 Dr2 = *(const float4*)(Db + 2 * 256 + hq * 4);
    const float4 Dr3 = *(const float4*)(Db + 3 * 256 + hq * 4);
    // Dp[p][i] = {D[t0+2p][4hq+i], D[t0+2p+1][4hq+i]}
    f32x2 Dp[2][4];
    Dp[0][0] = (f32x2){Dr0.x, Dr1.x}; Dp[0][1] = (f32x2){Dr0.y, Dr1.y};
    Dp[0][2] = (f32x2){Dr0.z, Dr1.z}; Dp[0][3] = (f32x2){Dr0.w, Dr1.w};
    Dp[1][0] = (f32x2){Dr2.x, Dr3.x}; Dp[1][1] = (f32x2){Dr2.y, Dr3.y};
    Dp[1][2] = (f32x2){Dr2.z, Dr3.z}; Dp[1][3] = (f32x2){Dr2.w, Dr3.w};
    const f32x2 v0 = (f32x2){vq.x, vq.x};
    const f32x2 v1 = (f32x2){vq.y, vq.y};
    const f32x2 v2 = (f32x2){vq.z, vq.z};
    const f32x2 v3 = (f32x2){vq.w, vq.w};
    const uint2* Ah = Ab + ((size_t)hq << 10) + lane;
#pragma unroll
    for (int lb = 0; lb < 16; ++lb) {
      const uint2 aq = Ah[lb * 64];
      const f32x2 a0 = (f32x2){bfbits2f(aq.x), bfbits2f(aq.x)};
      const f32x2 a1 = (f32x2){bfhi2f(aq.x),   bfhi2f(aq.x)};
      const f32x2 a2 = (f32x2){bfbits2f(aq.y), bfbits2f(aq.y)};
      const f32x2 a3 = (f32x2){bfhi2f(aq.y),   bfhi2f(aq.y)};
      const f32x2 one = (f32x2){1.f, 1.f};
#pragma unroll
      for (int p = 0; p < 2; ++p) {
        const f32x2 d0 = a0 * Dp[p][0] + one;
        const f32x2 d1 = a1 * Dp[p][1] + one;
        const f32x2 d2 = a2 * Dp[p][2] + one;
        const f32x2 d3 = a3 * Dp[p][3] + one;
        const f32x2 n01 = v0 * d1 + v1 * d0;
        const f32x2 n23 = v2 * d3 + v3 * d2;
        const f32x2 d01 = d0 * d1;
        const f32x2 d23 = d2 * d3;
        const f32x2 nf = n01 * d23 + n23 * d01;
        const f32x2 df = d01 * d23;
        const f32x2 r = (f32x2){FAST_RCP(df.x), FAST_RCP(df.y)};
        acc2[p][lb] += nf * r;
      }
    }
  }
  // softmax over l (score = -2*acc; global constants cancel)
#pragma unroll
  for (int p = 0; p < 2; ++p)
#pragma unroll
    for (int half = 0; half < 2; ++half) {
      const int tt = 2 * p + half;
      float s[16];
      float m = -1e30f;
#pragma unroll
      for (int lb = 0; lb < 16; ++lb) {
        s[lb] = -2.f * (half ? acc2[p][lb].y : acc2[p][lb].x);
        m = fmaxf(m, s[lb]);
      }
      for (int off = 32; off > 0; off >>= 1) m = fmaxf(m, __shfl_xor(m, off, 64));
      float pr[16];
      float sum = 0.f;
#pragma unroll
      for (int lb = 0; lb < 16; ++lb) {
        pr[lb] = exp2f((s[lb] - m) * LOG2E);
        sum += pr[lb];
      }
      for (int off = 32; off > 0; off >>= 1) sum += __shfl_xor(sum, off, 64);
      const float rs = 1.f / sum;
      float* op = out + ((size_t)(b * 1024) + (t0 + tt)) * 1024 + lane;
#pragma unroll
      for (int lb = 0; lb < 16; ++lb) op[lb * 64] = pr[lb] * rs;
    }
}

// ---------------------------------------------------------------------------
extern "C" void kernel_launch(void* const* d_in, const int* in_sizes, int n_in,
                              void* d_out, int out_size, void* d_ws, size_t ws_size,
                              hipStream_t stream) {
  (void)in_sizes; (void)n_in; (void)out_size; (void)ws_size;
  const float* x  = (const float*)d_in[0];
  const float* Wk = (const float*)d_in[1];
  const float* Wr = (const float*)d_in[2];
  const float* bb = (const float*)d_in[3];
  const float* W1 = (const float*)d_in[4];
  const float* b1 = (const float*)d_in[5];
  const float* W2 = (const float*)d_in[6];
  const float* b2 = (const float*)d_in[7];
  const float* V  = (const float*)d_in[8];
  // d_in[9] = bV : constant over l, cancels in softmax.

  char* ws = (char*)d_ws;
  float*          Dm   = (float*)(ws);                          // 64 MiB f32 D[b][t][h]
  uint2*          ATq  = (uint2*)(ws + 67108864);               // 32 MiB bf16 A h-quads
  unsigned short* hseq = (unsigned short*)(ws + 100663296);     // 32 MiB bf16 h_t
  float*          xz   = (float*)(ws + 134217728);              // 256 KiB
  float* out = (float*)d_out;

  hipLaunchKernelGGL(k2_xz, dim3(64), dim3(256), 0, stream, x, Wk, bb, xz);
  hipLaunchKernelGGL(k3_fat, dim3(64 + 4096), dim3(512), 0, stream,
                     xz, Wr, hseq, x, W1, b1, ATq);
  hipLaunchKernelGGL(k3b_w2d, dim3(4096), dim3(256), 0, stream,
                     (const unsigned int*)hseq, W2, b2, Dm);
  hipLaunchKernelGGL(k4_attn, dim3(4096), dim3(256), 0, stream, ATq, Dm, V, out);
}

// Round 12
// 4099.652 us; speedup vs baseline: 1.0669x; 1.0669x over previous
//
#include <hip/hip_runtime.h>
#include <hip/hip_bf16.h>

// ---------------------------------------------------------------------------
// PointerLSTM: B=64, L=1024, D=256, H=256, T=1024 steps.
//   tanh(x) = 1 - 2/(1 + e^{2x});  e^{2(a+d)} = A*D with A=e^{2a}, D=e^{2d}
//   score_l = const - 2*sum_h V_h/(1+A_lh*D_th)   -> const cancels in softmax
// R11 -> R12: amdgpu_waves_per_eu(2,2) was a NO-OP (identical counters).
// Stop fighting the 128-VGPR budget; FIT it: recurrence now 1024 threads,
// 1 column/thread -> 96 weight regs + ~20 temps < 128. 32 pairs stay in LDS
// (128 KiB). Same math, same CHEAP_BAR structure. Fused w1e GEMM gets
// 16 waves/CU. k4 keeps R11's XCD swizzle (neutral-to-positive).
// ---------------------------------------------------------------------------

#define LOG2E  1.4426950408889634f
#define C2LOG2E 2.8853900817779268f   // 2*log2(e)

typedef float f32x2 __attribute__((ext_vector_type(2)));

__device__ __forceinline__ unsigned f2bf(float f) {
  unsigned u = __builtin_bit_cast(unsigned, f);
  return (u + 0x7fffu + ((u >> 16) & 1u)) >> 16;   // round-to-nearest-even
}
// bf16 bits in the LOW half of `bits` -> float. (High half ignored.)
__device__ __forceinline__ float bfbits2f(unsigned bits) {
  return __builtin_bit_cast(float, bits << 16);
}
// bf16 bits in the HIGH half of `bits` -> float (no shift needed).
__device__ __forceinline__ float bfhi2f(unsigned bits) {
  return __builtin_bit_cast(float, bits & 0xffff0000u);
}

// lgkmcnt-only barrier: skips __syncthreads()'s vmcnt(0) drain (in-flight
// global stores are NOT needed by the other threads; only LDS data crosses).
#define CHEAP_BAR()                                            \
  do {                                                         \
    asm volatile("s_waitcnt lgkmcnt(0)\n\ts_barrier" ::: "memory"); \
    __builtin_amdgcn_sched_barrier(0);                         \
  } while (0)

#if defined(__has_builtin)
#  if __has_builtin(__builtin_amdgcn_fdot2_f32_bf16)
#    define HAS_DOT2_BF16 1
#  endif
#endif

#if defined(HAS_DOT2_BF16)
typedef __bf16 bf16x2v __attribute__((ext_vector_type(2)));
__device__ __forceinline__ float dot2bf(unsigned w, unsigned h, float acc) {
  return __builtin_amdgcn_fdot2_f32_bf16(__builtin_bit_cast(bf16x2v, w),
                                         __builtin_bit_cast(bf16x2v, h), acc, false);
}
#else
__device__ __forceinline__ float dot2bf(unsigned w, unsigned h, float acc) {
  float wl = __builtin_bit_cast(float, w << 16);
  float wh = __builtin_bit_cast(float, w & 0xffff0000u);
  float hl = __builtin_bit_cast(float, h << 16);
  float hh = __builtin_bit_cast(float, h & 0xffff0000u);
  return fmaf(wh, hh, fmaf(wl, hl, acc));
}
#endif

#if defined(__has_builtin) && __has_builtin(__builtin_amdgcn_rcpf)
#  define FAST_RCP(x) __builtin_amdgcn_rcpf(x)
#else
#  define FAST_RCP(x) (1.0f / (x))
#endif

__device__ __forceinline__ float fast_sigmoid(float x) {
  return FAST_RCP(1.f + exp2f(-LOG2E * x));
}
__device__ __forceinline__ float fast_tanh(float x) {
  return 1.f - 2.f * FAST_RCP(1.f + exp2f(C2LOG2E * x));
}

// --- k2: xz[b][j] = x[b][1023][:] @ Wk[:,j] + b[j]
__global__ __launch_bounds__(256) void k2_xz(const float* __restrict__ x,
                                             const float* __restrict__ Wk,
                                             const float* __restrict__ bvec,
                                             float* __restrict__ xz) {
  const int b = blockIdx.x, tid = threadIdx.x;
  float acc[4] = {bvec[tid], bvec[256 + tid], bvec[512 + tid], bvec[768 + tid]};
  const float* xr = x + ((size_t)b * 1024 + 1023) * 256;
  for (int d0 = 0; d0 < 256; d0 += 4) {
    const float4 xv = *(const float4*)(xr + d0);
#pragma unroll
    for (int i = 0; i < 4; ++i) {
      const float xs = (i == 0) ? xv.x : (i == 1) ? xv.y : (i == 2) ? xv.z : xv.w;
#pragma unroll
      for (int q = 0; q < 4; ++q)
        acc[q] = fmaf(xs, Wk[(size_t)(d0 + i) * 1024 + q * 256 + tid], acc[q]);
    }
  }
#pragma unroll
  for (int q = 0; q < 4; ++q) xz[b * 1024 + q * 256 + tid] = acc[q];
}

// --- k3_fat (1024 threads): blocks 0..63 = LSTM recurrence (one per batch);
//             blocks 64..4159 = w1e GEMM, filling idle CUs.
// Recurrence: thread owns ONE column (tid). Weight bf16x2 row-pairs:
//   pairs 0..95   in VGPRs (96 regs/thread -> fits the 128 budget, no spill)
//   pairs 96..127 in LDS   (32 pairs x 1024 cols x 4B = 128 KiB)
// z exchange: threads 256..1023 export a -> z_lds[tid-256] (zf/zg/zo);
// gates on threads 0..255 (zi = own accumulator).
__global__ __launch_bounds__(1024)
void k3_fat(const float* __restrict__ xz,
            const float* __restrict__ Wr,
            unsigned short* __restrict__ hseq,
            const float* __restrict__ x,
            const float* __restrict__ W1,
            const float* __restrict__ b1,
            uint2* __restrict__ ATq) {
  __shared__ __align__(16) unsigned smem[32768 + 768 + 128];  // 131.5 KiB
  const int tid = threadIdx.x;
  if (blockIdx.x < 64) {
    // ---------------- recurrence path ----------------
    unsigned* Wtail = smem;                       // [8][1024][4] pairs 96..127
    float*    z_lds = (float*)(smem + 32768);     // [768] zf,zg,zo exports
    unsigned* h_pk  = smem + 32768 + 768;         // [128] h as bf16x2
    const int b = blockIdx.x;
    const int col = tid;

    unsigned w[96];
#pragma unroll
    for (int p = 0; p < 96; ++p) {
      w[p] = f2bf(Wr[(size_t)(2 * p) * 1024 + col]) |
             (f2bf(Wr[(size_t)(2 * p + 1) * 1024 + col]) << 16);
    }
#pragma unroll
    for (int gg = 0; gg < 8; ++gg) {
#pragma unroll
      for (int d = 0; d < 4; ++d) {
        const int p = 96 + gg * 4 + d;
        Wtail[(gg * 1024 + col) * 4 + d] =
            f2bf(Wr[(size_t)(2 * p) * 1024 + col]) |
            (f2bf(Wr[(size_t)(2 * p + 1) * 1024 + col]) << 16);
      }
    }
    if (tid < 128) h_pk[tid] = 0u;
    const float za = xz[b * 1024 + col];
    float c = 0.f;
    CHEAP_BAR();

    for (int t = 0; t < 1024; ++t) {
      float a0 = za, a1 = 0.f;
#pragma unroll
      for (int g = 0; g < 12; ++g) {
        const uint4 hp = *(const uint4*)&h_pk[4 * g];
        a0 = dot2bf(w[4 * g + 0], hp.x, a0);
        a0 = dot2bf(w[4 * g + 1], hp.y, a0);
        a0 = dot2bf(w[4 * g + 2], hp.z, a0);
        a0 = dot2bf(w[4 * g + 3], hp.w, a0);
      }
#pragma unroll
      for (int g = 12; g < 24; ++g) {
        const uint4 hp = *(const uint4*)&h_pk[4 * g];
        a1 = dot2bf(w[4 * g + 0], hp.x, a1);
        a1 = dot2bf(w[4 * g + 1], hp.y, a1);
        a1 = dot2bf(w[4 * g + 2], hp.z, a1);
        a1 = dot2bf(w[4 * g + 3], hp.w, a1);
      }
#pragma unroll
      for (int gg = 0; gg < 8; ++gg) {
        const uint4 hp = *(const uint4*)&h_pk[96 + 4 * gg];
        const uint4 wv = *(const uint4*)&Wtail[(gg * 1024 + col) * 4];
        float& r = (gg < 4) ? a0 : a1;
        r = dot2bf(wv.x, hp.x, r);
        r = dot2bf(wv.y, hp.y, r);
        r = dot2bf(wv.z, hp.z, r);
        r = dot2bf(wv.w, hp.w, r);
      }
      const float a = a0 + a1;
      // z export: threads 256..1023 hold zf/zg/zo for h-elem (tid&255)
      if (tid >= 256) z_lds[tid - 256] = a;
      CHEAP_BAR();
      // gates: thread<256 owns h-elem tid; zi = own column's accumulator.
      if (tid < 256) {
        const float zi = a;
        const float zf = z_lds[tid];
        const float zg = z_lds[tid + 256];
        const float zo = z_lds[tid + 512];
        const float ig = fast_sigmoid(zi);
        const float fg = fast_sigmoid(zf);
        const float gv = fast_tanh(zg);
        const float og = fast_sigmoid(zo);
        c = fmaf(fg, c, ig * gv);
        const float h = og * fast_tanh(c);
        const unsigned short hb = (unsigned short)f2bf(h);
        ((unsigned short*)h_pk)[tid] = hb;
        hseq[(size_t)(t * 64 + b) * 256 + tid] = hb;   // fire-and-forget
      }
      CHEAP_BAR();
    }
  } else {
    // ---------------- w1e GEMM path ----------------
    unsigned short* tile = (unsigned short*)smem;     // [256][16], 8 KiB
    const int bid = blockIdx.x - 64;
    const int b  = bid >> 6;
    const int lb = bid & 63;            // 16 l-rows per block
    const int h = tid & 255;
    const int qr = tid >> 8;            // quarter: rows qr*4 .. qr*4+3
    float acc[4];
    const float bias = b1[h];
#pragma unroll
    for (int r = 0; r < 4; ++r) acc[r] = bias;
    const float* xb = x + ((size_t)(b * 1024 + lb * 16 + qr * 4)) * 256;
    for (int d0 = 0; d0 < 256; d0 += 4) {
      const float w0 = W1[(d0 + 0) * 256 + h];
      const float w1 = W1[(d0 + 1) * 256 + h];
      const float w2 = W1[(d0 + 2) * 256 + h];
      const float w3 = W1[(d0 + 3) * 256 + h];
#pragma unroll
      for (int r = 0; r < 4; ++r) {
        const float4 xv = *(const float4*)(xb + r * 256 + d0);
        acc[r] = fmaf(xv.x, w0, acc[r]);
        acc[r] = fmaf(xv.y, w1, acc[r]);
        acc[r] = fmaf(xv.z, w2, acc[r]);
        acc[r] = fmaf(xv.w, w3, acc[r]);
      }
    }
#pragma unroll
    for (int r = 0; r < 4; ++r)
      tile[h * 16 + qr * 4 + r] = (unsigned short)f2bf(exp2f(C2LOG2E * acc[r]));
    __syncthreads();
    // write phase: 1024 uint2 outputs (hq, lloc), 1 per thread, coalesced.
    {
      const int hq = tid >> 4, lloc = tid & 15;
      const unsigned s0 = tile[(4 * hq + 0) * 16 + lloc];
      const unsigned s1 = tile[(4 * hq + 1) * 16 + lloc];
      const unsigned s2 = tile[(4 * hq + 2) * 16 + lloc];
      const unsigned s3 = tile[(4 * hq + 3) * 16 + lloc];
      uint2 val;
      val.x = s0 | (s1 << 16);
      val.y = s2 | (s3 << 16);
      ATq[(((size_t)(b * 64 + hq)) << 10) + lb * 16 + lloc] = val;
    }
  }
}

// --- k3b: w2d = hseq @ W2 + b2 for all (t,b); store D[b][t][h] = f32(exp2(C2*w2d))
__global__ __launch_bounds__(256) void k3b_w2d(const unsigned int* __restrict__ hseq,
                                               const float* __restrict__ W2,
                                               const float* __restrict__ b2,
                                               float* __restrict__ D) {
  const int r0 = blockIdx.x * 16;   // rows (t*64+b); 16 rows share one t
  const int h = threadIdx.x;
  float acc[16];
  const float bias = b2[h];
#pragma unroll
  for (int r = 0; r < 16; ++r) acc[r] = bias;
  for (int m0 = 0; m0 < 128; m0 += 2) {   // 2 dwords = 4 k values
    const float w0 = W2[(size_t)(2 * m0 + 0) * 256 + h];
    const float w1 = W2[(size_t)(2 * m0 + 1) * 256 + h];
    const float w2 = W2[(size_t)(2 * m0 + 2) * 256 + h];
    const float w3 = W2[(size_t)(2 * m0 + 3) * 256 + h];
#pragma unroll
    for (int r = 0; r < 16; ++r) {
      const uint2 hp = *(const uint2*)&hseq[(size_t)(r0 + r) * 128 + m0];
      acc[r] = fmaf(bfbits2f(hp.x),       w0, acc[r]);
      acc[r] = fmaf(bfbits2f(hp.x >> 16), w1, acc[r]);
      acc[r] = fmaf(bfbits2f(hp.y),       w2, acc[r]);
      acc[r] = fmaf(bfbits2f(hp.y >> 16), w3, acc[r]);
    }
  }
  const int t = r0 >> 6;
  const int bb0 = r0 & 63;
#pragma unroll
  for (int r = 0; r < 16; ++r) {
    D[((size_t)(bb0 + r) * 1024 + t) * 256 + h] = exp2f(C2LOG2E * acc[r]);
  }
}

// --- k4: attention scores + softmax (R7 scalar math — known good) + XCD
// swizzle: logical block l = (bid%8)*512 + bid/8 so all 64 t-blocks of one b
// land on one XCD's L2 (ATq slice 512KB re-used instead of re-fetched).
__global__ __launch_bounds__(256, 3) void k4_attn(const uint2* __restrict__ ATq,
                                                  const float* __restrict__ Dm,
                                                  const float* __restrict__ V,
                                                  float* __restrict__ out) {
  const int l  = (blockIdx.x & 7) * 512 + (blockIdx.x >> 3);   // bijective, 4096%8==0
  const int b  = l >> 6;
  const int tb = l & 63;
  const int wv = threadIdx.x >> 6;
  const int lane = threadIdx.x & 63;
  const int t0 = tb * 16 + wv * 4;
  const uint2* Ab = ATq + (((size_t)b) << 16);           // b*64*1024
  const float* Db = Dm + ((size_t)(b * 1024) + t0) * 256;
  f32x2 acc2[2][16];   // [t-pair][lb]; .x = t0+2p, .y = t0+2p+1
#pragma unroll
  for (int p = 0; p < 2; ++p)
#pragma unroll
    for (int lb = 0; lb < 16; ++lb) acc2[p][lb] = (f32x2){0.f, 0.f};

  for (int hq = 0; hq < 64; ++hq) {
    const float4 vq  = *(const float4*)(V + hq * 4);
    const float4 Dr0 = *(const float4*)(Db + 0 * 256 + hq * 4);
    const float4 Dr1 = *(const float4*)(Db + 1 * 256 + hq * 4);
    const float4 Dr2 = *(const float4*)(Db + 2 * 256 + hq * 4);
    const float4 Dr3 = *(const float4*)(Db + 3 * 256 + hq * 4);
    // Dp[p][i] = {D[t0+2p][4hq+i], D[t0+2p+1][4hq+i]}
    f32x2 Dp[2][4];
    Dp[0][0] = (f32x2){Dr0.x, Dr1.x}; Dp[0][1] = (f32x2){Dr0.y, Dr1.y};
    Dp[0][2] = (f32x2){Dr0.z, Dr1.z}; Dp[0][3] = (f32x2){Dr0.w, Dr1.w};
    Dp[1][0] = (f32x2){Dr2.x, Dr3.x}; Dp[1][1] = (f32x2){Dr2.y, Dr3.y};
    Dp[1][2] = (f32x2){Dr2.z, Dr3.z}; Dp[1][3] = (f32x2){Dr2.w, Dr3.w};
    const f32x2 v0 = (f32x2){vq.x, vq.x};
    const f32x2 v1 = (f32x2){vq.y, vq.y};
    const f32x2 v2 = (f32x2){vq.z, vq.z};
    const f32x2 v3 = (f32x2){vq.w, vq.w};
    const uint2* Ah = Ab + ((size_t)hq << 10) + lane;
#pragma unroll
    for (int lb = 0; lb < 16; ++lb) {
      const uint2 aq = Ah[lb * 64];
      const f32x2 a0 = (f32x2){bfbits2f(aq.x), bfbits2f(aq.x)};
      const f32x2 a1 = (f32x2){bfhi2f(aq.x),   bfhi2f(aq.x)};
      const f32x2 a2 = (f32x2){bfbits2f(aq.y), bfbits2f(aq.y)};
      const f32x2 a3 = (f32x2){bfhi2f(aq.y),   bfhi2f(aq.y)};
      const f32x2 one = (f32x2){1.f, 1.f};
#pragma unroll
      for (int p = 0; p < 2; ++p) {
        const f32x2 d0 = a0 * Dp[p][0] + one;
        const f32x2 d1 = a1 * Dp[p][1] + one;
        const f32x2 d2 = a2 * Dp[p][2] + one;
        const f32x2 d3 = a3 * Dp[p][3] + one;
        const f32x2 n01 = v0 * d1 + v1 * d0;
        const f32x2 n23 = v2 * d3 + v3 * d2;
        const f32x2 d01 = d0 * d1;
        const f32x2 d23 = d2 * d3;
        const f32x2 nf = n01 * d23 + n23 * d01;
        const f32x2 df = d01 * d23;
        const f32x2 r = (f32x2){FAST_RCP(df.x), FAST_RCP(df.y)};
        acc2[p][lb] += nf * r;
      }
    }
  }
  // softmax over l (score = -2*acc; global constants cancel)
#pragma unroll
  for (int p = 0; p < 2; ++p)
#pragma unroll
    for (int half = 0; half < 2; ++half) {
      const int tt = 2 * p + half;
      float s[16];
      float m = -1e30f;
#pragma unroll
      for (int lb = 0; lb < 16; ++lb) {
        s[lb] = -2.f * (half ? acc2[p][lb].y : acc2[p][lb].x);
        m = fmaxf(m, s[lb]);
      }
      for (int off = 32; off > 0; off >>= 1) m = fmaxf(m, __shfl_xor(m, off, 64));
      float pr[16];
      float sum = 0.f;
#pragma unroll
      for (int lb = 0; lb < 16; ++lb) {
        pr[lb] = exp2f((s[lb] - m) * LOG2E);
        sum += pr[lb];
      }
      for (int off = 32; off > 0; off >>= 1) sum += __shfl_xor(sum, off, 64);
      const float rs = 1.f / sum;
      float* op = out + ((size_t)(b * 1024) + (t0 + tt)) * 1024 + lane;
#pragma unroll
      for (int lb = 0; lb < 16; ++lb) op[lb * 64] = pr[lb] * rs;
    }
}

// ---------------------------------------------------------------------------
extern "C" void kernel_launch(void* const* d_in, const int* in_sizes, int n_in,
                              void* d_out, int out_size, void* d_ws, size_t ws_size,
                              hipStream_t stream) {
  (void)in_sizes; (void)n_in; (void)out_size; (void)ws_size;
  const float* x  = (const float*)d_in[0];
  const float* Wk = (const float*)d_in[1];
  const float* Wr = (const float*)d_in[2];
  const float* bb = (const float*)d_in[3];
  const float* W1 = (const float*)d_in[4];
  const float* b1 = (const float*)d_in[5];
  const float* W2 = (const float*)d_in[6];
  const float* b2 = (const float*)d_in[7];
  const float* V  = (const float*)d_in[8];
  // d_in[9] = bV : constant over l, cancels in softmax.

  char* ws = (char*)d_ws;
  float*          Dm   = (float*)(ws);                          // 64 MiB f32 D[b][t][h]
  uint2*          ATq  = (uint2*)(ws + 67108864);               // 32 MiB bf16 A h-quads
  unsigned short* hseq = (unsigned short*)(ws + 100663296);     // 32 MiB bf16 h_t
  float*          xz   = (float*)(ws + 134217728);              // 256 KiB
  float* out = (float*)d_out;

  hipLaunchKernelGGL(k2_xz, dim3(64), dim3(256), 0, stream, x, Wk, bb, xz);
  hipLaunchKernelGGL(k3_fat, dim3(64 + 4096), dim3(1024), 0, stream,
                     xz, Wr, hseq, x, W1, b1, ATq);
  hipLaunchKernelGGL(k3b_w2d, dim3(4096), dim3(256), 0, stream,
                     (const unsigned int*)hseq, W2, b2, Dm);
  hipLaunchKernelGGL(k4_attn, dim3(4096), dim3(256), 0, stream, ATq, Dm, V, out);
}

// Round 13
// 3623.091 us; speedup vs baseline: 1.2072x; 1.1315x over previous
//
#include <hip/hip_runtime.h>
#include <hip/hip_bf16.h>

// ---------------------------------------------------------------------------
// PointerLSTM: B=64, L=1024, D=256, H=256, T=1024 steps.
//   tanh(x) = 1 - 2/(1 + e^{2x});  e^{2(a+d)} = A*D with A=e^{2a}, D=e^{2d}
//   score_l = const - 2*sum_h V_h/(1+A_lh*D_th)   -> const cancels in softmax
// R12 -> R13: k4 was 60% VALUBusy with exposed global-load latency (56 VGPRs,
// no prefetch depth). Now: A staged through a 2x8KB LDS double buffer with
// load-early/write-late split (T14), V/D prefetched into registers. Math
// byte-identical. k3_fat/k3b/k2 untouched.
// ---------------------------------------------------------------------------

#define LOG2E  1.4426950408889634f
#define C2LOG2E 2.8853900817779268f   // 2*log2(e)

typedef float f32x2 __attribute__((ext_vector_type(2)));

__device__ __forceinline__ unsigned f2bf(float f) {
  unsigned u = __builtin_bit_cast(unsigned, f);
  return (u + 0x7fffu + ((u >> 16) & 1u)) >> 16;   // round-to-nearest-even
}
// bf16 bits in the LOW half of `bits` -> float. (High half ignored.)
__device__ __forceinline__ float bfbits2f(unsigned bits) {
  return __builtin_bit_cast(float, bits << 16);
}
// bf16 bits in the HIGH half of `bits` -> float (no shift needed).
__device__ __forceinline__ float bfhi2f(unsigned bits) {
  return __builtin_bit_cast(float, bits & 0xffff0000u);
}

// lgkmcnt-only barrier: skips __syncthreads()'s vmcnt(0) drain (in-flight
// global stores are NOT needed by the other threads; only LDS data crosses).
#define CHEAP_BAR()                                            \
  do {                                                         \
    asm volatile("s_waitcnt lgkmcnt(0)\n\ts_barrier" ::: "memory"); \
    __builtin_amdgcn_sched_barrier(0);                         \
  } while (0)

#if defined(__has_builtin)
#  if __has_builtin(__builtin_amdgcn_fdot2_f32_bf16)
#    define HAS_DOT2_BF16 1
#  endif
#endif

#if defined(HAS_DOT2_BF16)
typedef __bf16 bf16x2v __attribute__((ext_vector_type(2)));
__device__ __forceinline__ float dot2bf(unsigned w, unsigned h, float acc) {
  return __builtin_amdgcn_fdot2_f32_bf16(__builtin_bit_cast(bf16x2v, w),
                                         __builtin_bit_cast(bf16x2v, h), acc, false);
}
#else
__device__ __forceinline__ float dot2bf(unsigned w, unsigned h, float acc) {
  float wl = __builtin_bit_cast(float, w << 16);
  float wh = __builtin_bit_cast(float, w & 0xffff0000u);
  float hl = __builtin_bit_cast(float, h << 16);
  float hh = __builtin_bit_cast(float, h & 0xffff0000u);
  return fmaf(wh, hh, fmaf(wl, hl, acc));
}
#endif

#if defined(__has_builtin) && __has_builtin(__builtin_amdgcn_rcpf)
#  define FAST_RCP(x) __builtin_amdgcn_rcpf(x)
#else
#  define FAST_RCP(x) (1.0f / (x))
#endif

__device__ __forceinline__ float fast_sigmoid(float x) {
  return FAST_RCP(1.f + exp2f(-LOG2E * x));
}
__device__ __forceinline__ float fast_tanh(float x) {
  return 1.f - 2.f * FAST_RCP(1.f + exp2f(C2LOG2E * x));
}

// --- k2: xz[b][j] = x[b][1023][:] @ Wk[:,j] + b[j]
__global__ __launch_bounds__(256) void k2_xz(const float* __restrict__ x,
                                             const float* __restrict__ Wk,
                                             const float* __restrict__ bvec,
                                             float* __restrict__ xz) {
  const int b = blockIdx.x, tid = threadIdx.x;
  float acc[4] = {bvec[tid], bvec[256 + tid], bvec[512 + tid], bvec[768 + tid]};
  const float* xr = x + ((size_t)b * 1024 + 1023) * 256;
  for (int d0 = 0; d0 < 256; d0 += 4) {
    const float4 xv = *(const float4*)(xr + d0);
#pragma unroll
    for (int i = 0; i < 4; ++i) {
      const float xs = (i == 0) ? xv.x : (i == 1) ? xv.y : (i == 2) ? xv.z : xv.w;
#pragma unroll
      for (int q = 0; q < 4; ++q)
        acc[q] = fmaf(xs, Wk[(size_t)(d0 + i) * 1024 + q * 256 + tid], acc[q]);
    }
  }
#pragma unroll
  for (int q = 0; q < 4; ++q) xz[b * 1024 + q * 256 + tid] = acc[q];
}

// --- k3_fat (1024 threads): blocks 0..63 = LSTM recurrence (one per batch);
//             blocks 64..4159 = w1e GEMM, filling idle CUs. (R12, unchanged.)
__global__ __launch_bounds__(1024)
void k3_fat(const float* __restrict__ xz,
            const float* __restrict__ Wr,
            unsigned short* __restrict__ hseq,
            const float* __restrict__ x,
            const float* __restrict__ W1,
            const float* __restrict__ b1,
            uint2* __restrict__ ATq) {
  __shared__ __align__(16) unsigned smem[32768 + 768 + 128];  // 131.5 KiB
  const int tid = threadIdx.x;
  if (blockIdx.x < 64) {
    // ---------------- recurrence path ----------------
    unsigned* Wtail = smem;                       // [8][1024][4] pairs 96..127
    float*    z_lds = (float*)(smem + 32768);     // [768] zf,zg,zo exports
    unsigned* h_pk  = smem + 32768 + 768;         // [128] h as bf16x2
    const int b = blockIdx.x;
    const int col = tid;

    unsigned w[96];
#pragma unroll
    for (int p = 0; p < 96; ++p) {
      w[p] = f2bf(Wr[(size_t)(2 * p) * 1024 + col]) |
             (f2bf(Wr[(size_t)(2 * p + 1) * 1024 + col]) << 16);
    }
#pragma unroll
    for (int gg = 0; gg < 8; ++gg) {
#pragma unroll
      for (int d = 0; d < 4; ++d) {
        const int p = 96 + gg * 4 + d;
        Wtail[(gg * 1024 + col) * 4 + d] =
            f2bf(Wr[(size_t)(2 * p) * 1024 + col]) |
            (f2bf(Wr[(size_t)(2 * p + 1) * 1024 + col]) << 16);
      }
    }
    if (tid < 128) h_pk[tid] = 0u;
    const float za = xz[b * 1024 + col];
    float c = 0.f;
    CHEAP_BAR();

    for (int t = 0; t < 1024; ++t) {
      float a0 = za, a1 = 0.f;
#pragma unroll
      for (int g = 0; g < 12; ++g) {
        const uint4 hp = *(const uint4*)&h_pk[4 * g];
        a0 = dot2bf(w[4 * g + 0], hp.x, a0);
        a0 = dot2bf(w[4 * g + 1], hp.y, a0);
        a0 = dot2bf(w[4 * g + 2], hp.z, a0);
        a0 = dot2bf(w[4 * g + 3], hp.w, a0);
      }
#pragma unroll
      for (int g = 12; g < 24; ++g) {
        const uint4 hp = *(const uint4*)&h_pk[4 * g];
        a1 = dot2bf(w[4 * g + 0], hp.x, a1);
        a1 = dot2bf(w[4 * g + 1], hp.y, a1);
        a1 = dot2bf(w[4 * g + 2], hp.z, a1);
        a1 = dot2bf(w[4 * g + 3], hp.w, a1);
      }
#pragma unroll
      for (int gg = 0; gg < 8; ++gg) {
        const uint4 hp = *(const uint4*)&h_pk[96 + 4 * gg];
        const uint4 wv = *(const uint4*)&Wtail[(gg * 1024 + col) * 4];
        float& r = (gg < 4) ? a0 : a1;
        r = dot2bf(wv.x, hp.x, r);
        r = dot2bf(wv.y, hp.y, r);
        r = dot2bf(wv.z, hp.z, r);
        r = dot2bf(wv.w, hp.w, r);
      }
      const float a = a0 + a1;
      // z export: threads 256..1023 hold zf/zg/zo for h-elem (tid&255)
      if (tid >= 256) z_lds[tid - 256] = a;
      CHEAP_BAR();
      // gates: thread<256 owns h-elem tid; zi = own column's accumulator.
      if (tid < 256) {
        const float zi = a;
        const float zf = z_lds[tid];
        const float zg = z_lds[tid + 256];
        const float zo = z_lds[tid + 512];
        const float ig = fast_sigmoid(zi);
        const float fg = fast_sigmoid(zf);
        const float gv = fast_tanh(zg);
        const float og = fast_sigmoid(zo);
        c = fmaf(fg, c, ig * gv);
        const float h = og * fast_tanh(c);
        const unsigned short hb = (unsigned short)f2bf(h);
        ((unsigned short*)h_pk)[tid] = hb;
        hseq[(size_t)(t * 64 + b) * 256 + tid] = hb;   // fire-and-forget
      }
      CHEAP_BAR();
    }
  } else {
    // ---------------- w1e GEMM path ----------------
    unsigned short* tile = (unsigned short*)smem;     // [256][16], 8 KiB
    const int bid = blockIdx.x - 64;
    const int b  = bid >> 6;
    const int lb = bid & 63;            // 16 l-rows per block
    const int h = tid & 255;
    const int qr = tid >> 8;            // quarter: rows qr*4 .. qr*4+3
    float acc[4];
    const float bias = b1[h];
#pragma unroll
    for (int r = 0; r < 4; ++r) acc[r] = bias;
    const float* xb = x + ((size_t)(b * 1024 + lb * 16 + qr * 4)) * 256;
    for (int d0 = 0; d0 < 256; d0 += 4) {
      const float w0 = W1[(d0 + 0) * 256 + h];
      const float w1 = W1[(d0 + 1) * 256 + h];
      const float w2 = W1[(d0 + 2) * 256 + h];
      const float w3 = W1[(d0 + 3) * 256 + h];
#pragma unroll
      for (int r = 0; r < 4; ++r) {
        const float4 xv = *(const float4*)(xb + r * 256 + d0);
        acc[r] = fmaf(xv.x, w0, acc[r]);
        acc[r] = fmaf(xv.y, w1, acc[r]);
        acc[r] = fmaf(xv.z, w2, acc[r]);
        acc[r] = fmaf(xv.w, w3, acc[r]);
      }
    }
#pragma unroll
    for (int r = 0; r < 4; ++r)
      tile[h * 16 + qr * 4 + r] = (unsigned short)f2bf(exp2f(C2LOG2E * acc[r]));
    __syncthreads();
    // write phase: 1024 uint2 outputs (hq, lloc), 1 per thread, coalesced.
    {
      const int hq = tid >> 4, lloc = tid & 15;
      const unsigned s0 = tile[(4 * hq + 0) * 16 + lloc];
      const unsigned s1 = tile[(4 * hq + 1) * 16 + lloc];
      const unsigned s2 = tile[(4 * hq + 2) * 16 + lloc];
      const unsigned s3 = tile[(4 * hq + 3) * 16 + lloc];
      uint2 val;
      val.x = s0 | (s1 << 16);
      val.y = s2 | (s3 << 16);
      ATq[(((size_t)(b * 64 + hq)) << 10) + lb * 16 + lloc] = val;
    }
  }
}

// --- k3b: w2d = hseq @ W2 + b2 for all (t,b); store D[b][t][h] = f32(exp2(C2*w2d))
__global__ __launch_bounds__(256) void k3b_w2d(const unsigned int* __restrict__ hseq,
                                               const float* __restrict__ W2,
                                               const float* __restrict__ b2,
                                               float* __restrict__ D) {
  const int r0 = blockIdx.x * 16;   // rows (t*64+b); 16 rows share one t
  const int h = threadIdx.x;
  float acc[16];
  const float bias = b2[h];
#pragma unroll
  for (int r = 0; r < 16; ++r) acc[r] = bias;
  for (int m0 = 0; m0 < 128; m0 += 2) {   // 2 dwords = 4 k values
    const float w0 = W2[(size_t)(2 * m0 + 0) * 256 + h];
    const float w1 = W2[(size_t)(2 * m0 + 1) * 256 + h];
    const float w2 = W2[(size_t)(2 * m0 + 2) * 256 + h];
    const float w3 = W2[(size_t)(2 * m0 + 3) * 256 + h];
#pragma unroll
    for (int r = 0; r < 16; ++r) {
      const uint2 hp = *(const uint2*)&hseq[(size_t)(r0 + r) * 128 + m0];
      acc[r] = fmaf(bfbits2f(hp.x),       w0, acc[r]);
      acc[r] = fmaf(bfbits2f(hp.x >> 16), w1, acc[r]);
      acc[r] = fmaf(bfbits2f(hp.y),       w2, acc[r]);
      acc[r] = fmaf(bfbits2f(hp.y >> 16), w3, acc[r]);
    }
  }
  const int t = r0 >> 6;
  const int bb0 = r0 & 63;
#pragma unroll
  for (int r = 0; r < 16; ++r) {
    D[((size_t)(bb0 + r) * 1024 + t) * 256 + h] = exp2f(C2LOG2E * acc[r]);
  }
}

// --- k4: attention scores + softmax (R7 scalar math, byte-identical) with
// 2x8KB LDS double-buffered A-tile (load-early/write-late) + reg D/V prefetch.
__global__ __launch_bounds__(256, 3) void k4_attn(const uint2* __restrict__ ATq,
                                                  const float* __restrict__ Dm,
                                                  const float* __restrict__ V,
                                                  float* __restrict__ out) {
  __shared__ __align__(16) uint2 Abuf[2][1024];   // 16 KiB
  const int l  = (blockIdx.x & 7) * 512 + (blockIdx.x >> 3);   // XCD swizzle
  const int b  = l >> 6;
  const int tb = l & 63;
  const int tid  = threadIdx.x;
  const int wv   = tid >> 6;
  const int lane = tid & 63;
  const int t0 = tb * 16 + wv * 4;
  const uint2* Ab = ATq + (((size_t)b) << 16);           // b*64*1024
  const float* Db = Dm + ((size_t)(b * 1024) + t0) * 256;
  f32x2 acc2[2][16];   // [t-pair][lb]; .x = t0+2p, .y = t0+2p+1
#pragma unroll
  for (int p = 0; p < 2; ++p)
#pragma unroll
    for (int lb = 0; lb < 16; ++lb) acc2[p][lb] = (f32x2){0.f, 0.f};

  // prologue: stage hq=0 into Abuf[0]; prefetch V/D for hq=0.
  {
    const uint4 s0 = *(const uint4*)(Ab + 2 * tid);
    const uint4 s1 = *(const uint4*)(Ab + 512 + 2 * tid);
    *(uint4*)&Abuf[0][2 * tid] = s0;
    *(uint4*)&Abuf[0][512 + 2 * tid] = s1;
  }
  float4 vq  = *(const float4*)(V);
  float4 Dr0 = *(const float4*)(Db + 0 * 256);
  float4 Dr1 = *(const float4*)(Db + 1 * 256);
  float4 Dr2 = *(const float4*)(Db + 2 * 256);
  float4 Dr3 = *(const float4*)(Db + 3 * 256);
  __syncthreads();
  int cur = 0;

  for (int hq = 0; hq < 64; ++hq) {
    // issue next-tile loads EARLY (clamped on last iter; redundant but safe)
    const int hn = (hq < 63) ? hq + 1 : 63;
    const uint4 s0 = *(const uint4*)(Ab + ((size_t)hn << 10) + 2 * tid);
    const uint4 s1 = *(const uint4*)(Ab + ((size_t)hn << 10) + 512 + 2 * tid);
    const float4 nvq  = *(const float4*)(V + hn * 4);
    const float4 nDr0 = *(const float4*)(Db + 0 * 256 + hn * 4);
    const float4 nDr1 = *(const float4*)(Db + 1 * 256 + hn * 4);
    const float4 nDr2 = *(const float4*)(Db + 2 * 256 + hn * 4);
    const float4 nDr3 = *(const float4*)(Db + 3 * 256 + hn * 4);

    // Dp[p][i] = {D[t0+2p][4hq+i], D[t0+2p+1][4hq+i]}
    f32x2 Dp[2][4];
    Dp[0][0] = (f32x2){Dr0.x, Dr1.x}; Dp[0][1] = (f32x2){Dr0.y, Dr1.y};
    Dp[0][2] = (f32x2){Dr0.z, Dr1.z}; Dp[0][3] = (f32x2){Dr0.w, Dr1.w};
    Dp[1][0] = (f32x2){Dr2.x, Dr3.x}; Dp[1][1] = (f32x2){Dr2.y, Dr3.y};
    Dp[1][2] = (f32x2){Dr2.z, Dr3.z}; Dp[1][3] = (f32x2){Dr2.w, Dr3.w};
    const f32x2 v0 = (f32x2){vq.x, vq.x};
    const f32x2 v1 = (f32x2){vq.y, vq.y};
    const f32x2 v2 = (f32x2){vq.z, vq.z};
    const f32x2 v3 = (f32x2){vq.w, vq.w};
#pragma unroll
    for (int lb = 0; lb < 16; ++lb) {
      const uint2 aq = Abuf[cur][lb * 64 + lane];   // ds_read_b64, 2-way=free
      const f32x2 a0 = (f32x2){bfbits2f(aq.x), bfbits2f(aq.x)};
      const f32x2 a1 = (f32x2){bfhi2f(aq.x),   bfhi2f(aq.x)};
      const f32x2 a2 = (f32x2){bfbits2f(aq.y), bfbits2f(aq.y)};
      const f32x2 a3 = (f32x2){bfhi2f(aq.y),   bfhi2f(aq.y)};
      const f32x2 one = (f32x2){1.f, 1.f};
#pragma unroll
      for (int p = 0; p < 2; ++p) {
        const f32x2 d0 = a0 * Dp[p][0] + one;
        const f32x2 d1 = a1 * Dp[p][1] + one;
        const f32x2 d2 = a2 * Dp[p][2] + one;
        const f32x2 d3 = a3 * Dp[p][3] + one;
        const f32x2 n01 = v0 * d1 + v1 * d0;
        const f32x2 n23 = v2 * d3 + v3 * d2;
        const f32x2 d01 = d0 * d1;
        const f32x2 d23 = d2 * d3;
        const f32x2 nf = n01 * d23 + n23 * d01;
        const f32x2 df = d01 * d23;
        const f32x2 r = (f32x2){FAST_RCP(df.x), FAST_RCP(df.y)};
        acc2[p][lb] += nf * r;
      }
    }
    // write-late: park next tile in the alternate buffer, then barrier.
    *(uint4*)&Abuf[cur ^ 1][2 * tid] = s0;
    *(uint4*)&Abuf[cur ^ 1][512 + 2 * tid] = s1;
    __syncthreads();
    cur ^= 1;
    vq = nvq; Dr0 = nDr0; Dr1 = nDr1; Dr2 = nDr2; Dr3 = nDr3;
  }

  // softmax over l (score = -2*acc; global constants cancel)
#pragma unroll
  for (int p = 0; p < 2; ++p)
#pragma unroll
    for (int half = 0; half < 2; ++half) {
      const int tt = 2 * p + half;
      float s[16];
      float m = -1e30f;
#pragma unroll
      for (int lb = 0; lb < 16; ++lb) {
        s[lb] = -2.f * (half ? acc2[p][lb].y : acc2[p][lb].x);
        m = fmaxf(m, s[lb]);
      }
      for (int off = 32; off > 0; off >>= 1) m = fmaxf(m, __shfl_xor(m, off, 64));
      float pr[16];
      float sum = 0.f;
#pragma unroll
      for (int lb = 0; lb < 16; ++lb) {
        pr[lb] = exp2f((s[lb] - m) * LOG2E);
        sum += pr[lb];
      }
      for (int off = 32; off > 0; off >>= 1) sum += __shfl_xor(sum, off, 64);
      const float rs = 1.f / sum;
      float* op = out + ((size_t)(b * 1024) + (t0 + tt)) * 1024 + lane;
#pragma unroll
      for (int lb = 0; lb < 16; ++lb) op[lb * 64] = pr[lb] * rs;
    }
}

// ---------------------------------------------------------------------------
extern "C" void kernel_launch(void* const* d_in, const int* in_sizes, int n_in,
                              void* d_out, int out_size, void* d_ws, size_t ws_size,
                              hipStream_t stream) {
  (void)in_sizes; (void)n_in; (void)out_size; (void)ws_size;
  const float* x  = (const float*)d_in[0];
  const float* Wk = (const float*)d_in[1];
  const float* Wr = (const float*)d_in[2];
  const float* bb = (const float*)d_in[3];
  const float* W1 = (const float*)d_in[4];
  const float* b1 = (const float*)d_in[5];
  const float* W2 = (const float*)d_in[6];
  const float* b2 = (const float*)d_in[7];
  const float* V  = (const float*)d_in[8];
  // d_in[9] = bV : constant over l, cancels in softmax.

  char* ws = (char*)d_ws;
  float*          Dm   = (float*)(ws);                          // 64 MiB f32 D[b][t][h]
  uint2*          ATq  = (uint2*)(ws + 67108864);               // 32 MiB bf16 A h-quads
  unsigned short* hseq = (unsigned short*)(ws + 100663296);     // 32 MiB bf16 h_t
  float*          xz   = (float*)(ws + 134217728);              // 256 KiB
  float* out = (float*)d_out;

  hipLaunchKernelGGL(k2_xz, dim3(64), dim3(256), 0, stream, x, Wk, bb, xz);
  hipLaunchKernelGGL(k3_fat, dim3(64 + 4096), dim3(1024), 0, stream,
                     xz, Wr, hseq, x, W1, b1, ATq);
  hipLaunchKernelGGL(k3b_w2d, dim3(4096), dim3(256), 0, stream,
                     (const unsigned int*)hseq, W2, b2, Dm);
  hipLaunchKernelGGL(k4_attn, dim3(4096), dim3(256), 0, stream, ATq, Dm, V, out);
}